// Round 2
// baseline (73.561 us; speedup 1.0000x reference)
//
#include <hip/hip_runtime.h>

// t [32,8192] f32, control_points [22,3,10] f32.
// Outputs: pos, vel, acc each [32,8192,22,3] f32, concatenated flat.
#define NPTS      (32 * 8192)          // 262144 eval points
#define OUT_PER_PT 66                  // 22*3
#define TOTF      (NPTS * OUT_PER_PT)  // floats per output tensor
#define THREADS   256
#define PTS_PER_BLOCK 256
#define FD_H      1e-6
#define SB_STRIDE 24                   // floats/point in s_b: b0 @ [0..9], d1 @ [12..21] (16B-aligned)
#define CP_STRIDE 12                   // floats/jk in s_cp (16B-aligned rows)

// Faithful mirror of the reference _basis() (truncated Cox-de Boor: level r
// computes only indices 0..(10-r-1); tail forced to zero), in float64,
// with knots = np.linspace(0,1,8).astype(float32) padded by 3 on each side.
__device__ __forceinline__ void basis10(double t, double* __restrict__ N) {
    const float kf[14] = {
        0.0f, 0.0f, 0.0f, 0.0f,
        (float)(1.0 * (1.0 / 7.0)), (float)(2.0 * (1.0 / 7.0)),
        (float)(3.0 * (1.0 / 7.0)), (float)(4.0 * (1.0 / 7.0)),
        (float)(5.0 * (1.0 / 7.0)), (float)(6.0 * (1.0 / 7.0)),
        1.0f, 1.0f, 1.0f, 1.0f
    };
    double K[14];
#pragma unroll
    for (int i = 0; i < 14; ++i) K[i] = (double)kf[i];

#pragma unroll
    for (int i = 0; i < 10; ++i)
        N[i] = (t >= K[i] && t < K[i + 1]) ? 1.0 : 0.0;

#pragma unroll
    for (int r = 1; r <= 3; ++r) {
#pragma unroll
        for (int i = 0; i < 9; ++i) {
            if (i < 10 - r) {
                const float dlf = kf[i + r] - kf[i];         // f32 deltas, like numpy
                const float drf = kf[i + r + 1] - kf[i + 1];
                const double il = (dlf != 0.0f) ? 1.0 / (double)dlf : 0.0;
                const double ir = (drf != 0.0f) ? 1.0 / (double)drf : 0.0;
                N[i] = ((t - K[i]) * il) * N[i] + ((K[i + r + 1] - t) * ir) * N[i + 1];
            }
        }
        N[10 - r] = 0.0;
    }
}

__global__ __launch_bounds__(THREADS, 4)
void spline_kernel(const float* __restrict__ t_in,
                   const float* __restrict__ cp_in,
                   float* __restrict__ out) {
    __shared__ __align__(16) float s_cp[OUT_PER_PT * CP_STRIDE];       // 3.1 KB
    __shared__ __align__(16) float s_b[PTS_PER_BLOCK * SB_STRIDE];     // 24.6 KB

    const int tid = threadIdx.x;
    const int blk = blockIdx.x;

    // stage control points into padded rows (row jk at 48-B alignment)
    for (int i = tid; i < OUT_PER_PT * 10; i += THREADS) {
        const int jk = i / 10, r = i - jk * 10;
        s_cp[jk * CP_STRIDE + r] = cp_in[i];
    }

    // Phase 1: every thread computes its own point's f64 basis + f64 FD.
    {
        const int pt = blk * PTS_PER_BLOCK + tid;
        const double t = (double)t_in[pt];
        double Nt[10];
        basis10(t, Nt);
#pragma unroll
        for (int i = 0; i < 10; ++i) s_b[tid * SB_STRIDE + i] = (float)Nt[i];
        double Np[10], Nm[10];
        basis10(t + FD_H, Np);
        basis10(t - FD_H, Nm);
#pragma unroll
        for (int i = 0; i < 10; ++i)
            s_b[tid * SB_STRIDE + 12 + i] = (float)((Np[i] - Nm[i]) / (2.0 * FD_H));
    }
    __syncthreads();

    // Phase 2: 4 threads per point, direct scalar stores (L2 merges the
    // 16B-chunk/264B-stride pattern into full lines within the m-loop).
    const int q = tid & 3;
    const int psub = tid >> 2;
    for (int g = 0; g < 4; ++g) {
        const int p = g * 64 + psub;
        float b0[10], d1[10];
#pragma unroll
        for (int i = 0; i < 10; ++i) {
            b0[i] = s_b[p * SB_STRIDE + i];
            d1[i] = s_b[p * SB_STRIDE + 12 + i];
        }
        const size_t pbase = (size_t)(blk * PTS_PER_BLOCK + p) * OUT_PER_PT;
        float* __restrict__ op = out + pbase;
        float* __restrict__ ov = out + (size_t)TOTF + pbase;
        float* __restrict__ oa = out + (size_t)2 * TOTF + pbase;
        for (int m = 0; m < 17; ++m) {
            const int jk = q + 4 * m;
            if (jk < OUT_PER_PT) {
                float pf = 0.0f, vf = 0.0f;
#pragma unroll
                for (int i = 0; i < 10; ++i) {
                    const float c = s_cp[jk * CP_STRIDE + i];
                    pf += b0[i] * c;
                    vf += d1[i] * c;
                }
                op[jk] = pf;
                ov[jk] = vf;
                oa[jk] = vf;
            }
        }
    }
}

extern "C" void kernel_launch(void* const* d_in, const int* in_sizes, int n_in,
                              void* d_out, int out_size, void* d_ws, size_t ws_size,
                              hipStream_t stream) {
    const float* t_in  = (const float*)d_in[0];   // [32, 8192] f32
    const float* cp_in = (const float*)d_in[1];   // [22, 3, 10] f32
    float* out = (float*)d_out;

    const int blocks = NPTS / PTS_PER_BLOCK;      // 1024
    spline_kernel<<<blocks, THREADS, 0, stream>>>(t_in, cp_in, out);
}

// Round 3
// 47.667 us; speedup vs baseline: 1.5432x; 1.5432x over previous
//
#include <hip/hip_runtime.h>

// t [32,8192] f32, control_points [22,3,10] f32.
// Outputs: pos, vel, acc each [32,8192,22,3] f32, concatenated flat.
#define NPTS       (32 * 8192)                 // 262144 eval points
#define OUT_PER_PT 66                          // 22*3
#define TOTF       ((size_t)NPTS * OUT_PER_PT) // floats per output tensor
#define FD_H       1e-6

// Faithful mirror of the reference _basis() (truncated Cox-de Boor: level r
// computes only indices 0..(10-r-1); tail forced to zero), in float64,
// with knots = np.linspace(0,1,8).astype(float32) padded by 3 on each side.
__device__ __forceinline__ void basis10(double t, double* __restrict__ N) {
    const float kf[14] = {
        0.0f, 0.0f, 0.0f, 0.0f,
        (float)(1.0 * (1.0 / 7.0)), (float)(2.0 * (1.0 / 7.0)),
        (float)(3.0 * (1.0 / 7.0)), (float)(4.0 * (1.0 / 7.0)),
        (float)(5.0 * (1.0 / 7.0)), (float)(6.0 * (1.0 / 7.0)),
        1.0f, 1.0f, 1.0f, 1.0f
    };
    double K[14];
#pragma unroll
    for (int i = 0; i < 14; ++i) K[i] = (double)kf[i];

#pragma unroll
    for (int i = 0; i < 10; ++i)
        N[i] = (t >= K[i] && t < K[i + 1]) ? 1.0 : 0.0;

#pragma unroll
    for (int r = 1; r <= 3; ++r) {
#pragma unroll
        for (int i = 0; i < 9; ++i) {
            if (i < 10 - r) {
                const float dlf = kf[i + r] - kf[i];         // f32 deltas, like numpy
                const float drf = kf[i + r + 1] - kf[i + 1];
                const double il = (dlf != 0.0f) ? 1.0 / (double)dlf : 0.0;
                const double ir = (drf != 0.0f) ? 1.0 / (double)drf : 0.0;
                N[i] = ((t - K[i]) * il) * N[i] + ((K[i + r + 1] - t) * ir) * N[i + 1];
            }
        }
        N[10 - r] = 0.0;
    }
}

// One wave (64 threads) per block; each lane owns one eval point.
// b0/d1 live in registers (the lane that computed them uses them).
// cp_in is read with wave-uniform indices -> compiler emits s_load (SMEM/K$),
// removing all LDS traffic for the dot-product operands.
// LDS holds one 64x66 staging tile (16.9 KB); two passes (pos, then vel+acc)
// keep it single-buffered -> 9 blocks/CU.
__global__ __launch_bounds__(64)
void spline_kernel(const float* __restrict__ t_in,
                   const float* __restrict__ cp_in,
                   float* __restrict__ out) {
    __shared__ __align__(16) float s_stage[64 * OUT_PER_PT];   // 16896 B

    const int lane = threadIdx.x;               // 0..63
    const int blk  = blockIdx.x;                // 0..4095
    const int pt   = blk * 64 + lane;

    // ---- Phase 1: f64 basis + f64 central FD, all in registers ----
    float b0[10], d1[10];
    {
        const double t = (double)t_in[pt];
        double Nt[10], Np[10], Nm[10];
        basis10(t, Nt);
        basis10(t + FD_H, Np);
        basis10(t - FD_H, Nm);
#pragma unroll
        for (int i = 0; i < 10; ++i) {
            b0[i] = (float)Nt[i];
            d1[i] = (float)((Np[i] - Nm[i]) / (2.0 * FD_H));
        }
    }

    const size_t block_base = (size_t)blk * (64 * OUT_PER_PT); // dwords
    const float4* src = (const float4*)s_stage;
    const int NF4 = 64 * OUT_PER_PT / 4;        // 1056 float4 per tile

    // ---- Pass A: pos ----
    for (int j2 = 0; j2 < OUT_PER_PT / 2; ++j2) {       // jk = 2*j2, 2*j2+1
        float p0 = 0.0f, p1 = 0.0f;
#pragma unroll
        for (int i = 0; i < 10; ++i) {
            p0 += b0[i] * cp_in[(2 * j2) * 10 + i];     // uniform idx -> s_load
            p1 += b0[i] * cp_in[(2 * j2 + 1) * 10 + i];
        }
        *(float2*)&s_stage[lane * OUT_PER_PT + 2 * j2] = make_float2(p0, p1);
    }
    __syncthreads();   // single-wave barrier: cheap; orders LDS write->read
    {
        float4* dp = (float4*)(out + block_base);
        for (int k = lane; k < NF4; k += 64) dp[k] = src[k];
    }
    __syncthreads();   // copy-out reads done before pass B overwrites staging

    // ---- Pass B: vel (stored to both vel and acc) ----
    for (int j2 = 0; j2 < OUT_PER_PT / 2; ++j2) {
        float v0 = 0.0f, v1 = 0.0f;
#pragma unroll
        for (int i = 0; i < 10; ++i) {
            v0 += d1[i] * cp_in[(2 * j2) * 10 + i];
            v1 += d1[i] * cp_in[(2 * j2 + 1) * 10 + i];
        }
        *(float2*)&s_stage[lane * OUT_PER_PT + 2 * j2] = make_float2(v0, v1);
    }
    __syncthreads();
    {
        float4* dv = (float4*)(out + TOTF + block_base);
        float4* da = (float4*)(out + 2 * TOTF + block_base);
        for (int k = lane; k < NF4; k += 64) {
            const float4 v = src[k];
            dv[k] = v;
            da[k] = v;
        }
    }
}

extern "C" void kernel_launch(void* const* d_in, const int* in_sizes, int n_in,
                              void* d_out, int out_size, void* d_ws, size_t ws_size,
                              hipStream_t stream) {
    const float* t_in  = (const float*)d_in[0];   // [32, 8192] f32
    const float* cp_in = (const float*)d_in[1];   // [22, 3, 10] f32
    float* out = (float*)d_out;

    const int blocks = NPTS / 64;                 // 4096 blocks x 64 threads
    spline_kernel<<<blocks, 64, 0, stream>>>(t_in, cp_in, out);
}

// Round 4
// 41.970 us; speedup vs baseline: 1.7527x; 1.1358x over previous
//
#include <hip/hip_runtime.h>

// t [32,8192] f32, control_points [22,3,10] f32.
// Outputs: pos, vel, acc each [32,8192,22,3] f32, concatenated flat.
#define NPTS       (32 * 8192)            // 262144 eval points
#define OUT_PER_PT 66                     // 22*3
#define TOTF       (NPTS * OUT_PER_PT)    // 17,301,504 (fits int)
#define THREADS    256
#define PTS_PER_BLOCK 256
#define BSTRIDE    20                     // floats per basis row: b0[0..9] | d1[0..9]

// f32 knot values exactly as numpy linspace(0,1,8).astype(f32), clamped pad 3.
#define K4 ((float)(1.0 / 7.0))
#define K5 ((float)(2.0 / 7.0))
#define K6 ((float)(3.0 / 7.0))
#define K7 ((float)(4.0 / 7.0))
#define K8 ((float)(5.0 / 7.0))
#define K9 ((float)(6.0 / 7.0))

__device__ __forceinline__ void knots(float* kf) {
    kf[0] = 0.f; kf[1] = 0.f; kf[2] = 0.f; kf[3] = 0.f;
    kf[4] = K4; kf[5] = K5; kf[6] = K6; kf[7] = K7; kf[8] = K8; kf[9] = K9;
    kf[10] = 1.f; kf[11] = 1.f; kf[12] = 1.f; kf[13] = 1.f;
}

// Faithful f32 mirror of the reference truncated Cox-de Boor (level r computes
// indices 0..9-r; tail zeroed). Returns degree-3 values in N.
__device__ __forceinline__ void basis_f32(float t, float* __restrict__ N) {
    float kf[14]; knots(kf);
#pragma unroll
    for (int i = 0; i < 10; ++i) N[i] = (t >= kf[i] && t < kf[i + 1]) ? 1.0f : 0.0f;
#pragma unroll
    for (int r = 1; r <= 3; ++r) {
#pragma unroll
        for (int i = 0; i < 9; ++i) {
            if (i < 10 - r) {
                const float dl = kf[i + r] - kf[i];
                const float dr = kf[i + r + 1] - kf[i + 1];
                const float il = (dl != 0.0f) ? 1.0f / dl : 0.0f;
                const float ir = (dr != 0.0f) ? 1.0f / dr : 0.0f;
                N[i] = ((t - kf[i]) * il) * N[i] + ((kf[i + r + 1] - t) * ir) * N[i + 1];
            }
        }
        N[10 - r] = 0.0f;
    }
}

// Degree-3 basis AND its analytic first derivative.
// The truncated recursion yields the TRUE basis for indices 0..6 (7..9 zero),
// and true degree-2 values for indices 0..7, so
//   d1[i] = 3*( N2[i]/(k[i+3]-k[i]) - N2[i+1]/(k[i+4]-k[i+1]) ),  i=0..6.
__device__ __forceinline__ void basis_and_deriv(float t, float* __restrict__ b0,
                                                float* __restrict__ d1) {
    float kf[14]; knots(kf);
    float N[10];
#pragma unroll
    for (int i = 0; i < 10; ++i) N[i] = (t >= kf[i] && t < kf[i + 1]) ? 1.0f : 0.0f;
#pragma unroll
    for (int r = 1; r <= 2; ++r) {
#pragma unroll
        for (int i = 0; i < 9; ++i) {
            if (i < 10 - r) {
                const float dl = kf[i + r] - kf[i];
                const float dr = kf[i + r + 1] - kf[i + 1];
                const float il = (dl != 0.0f) ? 1.0f / dl : 0.0f;
                const float ir = (dr != 0.0f) ? 1.0f / dr : 0.0f;
                N[i] = ((t - kf[i]) * il) * N[i] + ((kf[i + r + 1] - t) * ir) * N[i + 1];
            }
        }
        N[10 - r] = 0.0f;
    }
    // N now holds degree-2 values (indices 0..7 true, 8..9 zero).
#pragma unroll
    for (int i = 0; i < 7; ++i) {
        const float dl = kf[i + 3] - kf[i];
        const float dr = kf[i + 4] - kf[i + 1];
        const float il = (dl != 0.0f) ? 3.0f / dl : 0.0f;
        const float ir = (dr != 0.0f) ? 3.0f / dr : 0.0f;
        d1[i] = il * N[i] - ir * N[i + 1];
    }
    d1[7] = 0.f; d1[8] = 0.f; d1[9] = 0.f;
    // final level -> degree-3 basis
#pragma unroll
    for (int i = 0; i < 7; ++i) {
        const float dl = kf[i + 3] - kf[i];
        const float dr = kf[i + 4] - kf[i + 1];
        const float il = (dl != 0.0f) ? 1.0f / dl : 0.0f;
        const float ir = (dr != 0.0f) ? 1.0f / dr : 0.0f;
        b0[i] = ((t - kf[i]) * il) * N[i] + ((kf[i + 4] - t) * ir) * N[i + 1];
    }
    b0[7] = 0.f; b0[8] = 0.f; b0[9] = 0.f;
}

__global__ __launch_bounds__(THREADS)
void spline_kernel(const float* __restrict__ t_in,
                   const float* __restrict__ cp_in,
                   float* __restrict__ out) {
    __shared__ __align__(16) float s_basis[PTS_PER_BLOCK * BSTRIDE]; // 20.0 KB
    __shared__ __align__(16) float s_cp[680];                        // 2.7 KB (660 + pad)

    const int tid = threadIdx.x;
    const int blk = blockIdx.x;

    // stage control points (pad zeros so slot-16 lanes can read rows 2,3 harmlessly)
    for (int i = tid; i < 680; i += THREADS)
        s_cp[i] = (i < 660) ? cp_in[i] : 0.0f;

    // ---- Phase 1: per-thread f32 basis + analytic derivative ----
    {
        const int pt = blk * PTS_PER_BLOCK + tid;
        const float t = t_in[pt];
        float b0[10], d1[10];
        basis_and_deriv(t, b0, d1);

        // Rare boundary lanes: reference's central FD has one side all-zero.
        const double td = (double)t;
        if (td < 1e-6) {                       // N(t-h) == 0  ->  d1 = N(t+h)/(2h)
            float Np[10];
            basis_f32((float)(td + 1e-6), Np);
#pragma unroll
            for (int i = 0; i < 10; ++i) d1[i] = Np[i] * 5.0e5f;
        } else if (td + 1e-6 >= 1.0) {         // N(t+h) == 0  ->  d1 = -N(t-h)/(2h)
            float Nm[10];
            basis_f32((float)(td - 1e-6), Nm);
#pragma unroll
            for (int i = 0; i < 10; ++i) d1[i] = -Nm[i] * 5.0e5f;
        }

        float* row = s_basis + tid * BSTRIDE;  // 80B-aligned
#pragma unroll
        for (int i = 0; i < 10; ++i) { row[i] = b0[i]; row[10 + i] = d1[i]; }
    }
    __syncthreads();

    // ---- Phase 2: output-centric, direct coalesced stores ----
    // 17 slots per point (16 float4 + 1 float2); 256 pts * 17 = 4352 = 17 * 256.
    const int out_blk_base = blk * (PTS_PER_BLOCK * OUT_PER_PT);
#pragma unroll 1
    for (int m = 0; m < 17; ++m) {
        const unsigned idx = (unsigned)(m * THREADS + tid);   // 0..4351
        const unsigned p    = idx / 17u;                      // local point
        const unsigned slot = idx - p * 17u;                  // 0..16

        const float* __restrict__ brow = s_basis + p * BSTRIDE;
        float b0r[10], d1r[10];
#pragma unroll
        for (int i = 0; i < 10; ++i) { b0r[i] = brow[i]; d1r[i] = brow[10 + i]; }

        const float* __restrict__ cpr = s_cp + slot * 40;     // rows jk0..jk0+3
        float pf[4], vf[4];
#pragma unroll
        for (int c = 0; c < 4; ++c) {
            float a = 0.f, b = 0.f;
#pragma unroll
            for (int i = 0; i < 10; ++i) {
                const float cv = cpr[c * 10 + i];
                a += b0r[i] * cv;
                b += d1r[i] * cv;
            }
            pf[c] = a; vf[c] = b;
        }

        // point rows are 264B -> only 8B-aligned; store as float2 pairs.
        const int obase = out_blk_base + (int)p * OUT_PER_PT + (int)slot * 4;
        float2* op = (float2*)(out + obase);
        float2* ov = (float2*)(out + TOTF + obase);
        float2* oa = (float2*)(out + 2 * TOTF + obase);
        op[0] = make_float2(pf[0], pf[1]);
        ov[0] = make_float2(vf[0], vf[1]);
        oa[0] = make_float2(vf[0], vf[1]);
        if (slot < 16) {
            op[1] = make_float2(pf[2], pf[3]);
            ov[1] = make_float2(vf[2], vf[3]);
            oa[1] = make_float2(vf[2], vf[3]);
        }
    }
}

extern "C" void kernel_launch(void* const* d_in, const int* in_sizes, int n_in,
                              void* d_out, int out_size, void* d_ws, size_t ws_size,
                              hipStream_t stream) {
    const float* t_in  = (const float*)d_in[0];   // [32, 8192] f32
    const float* cp_in = (const float*)d_in[1];   // [22, 3, 10] f32
    float* out = (float*)d_out;

    const int blocks = NPTS / PTS_PER_BLOCK;      // 1024
    spline_kernel<<<blocks, THREADS, 0, stream>>>(t_in, cp_in, out);
}

// Round 5
// 39.991 us; speedup vs baseline: 1.8394x; 1.0495x over previous
//
#include <hip/hip_runtime.h>

// t [32,8192] f32, control_points [22,3,10] f32.
// Outputs: pos, vel, acc each [32,8192,22,3] f32, concatenated flat.
#define NPTS       (32 * 8192)            // 262144 eval points
#define OUT_PER_PT 66                     // 22*3
#define TOTF       (NPTS * OUT_PER_PT)    // 17,301,504 (fits int)
#define THREADS    256
#define PTS_PER_BLOCK 256
#define BSTRIDE    24                     // floats/basis row: b0@[0..9], d1@[12..21]; 96B rows
#define CPT_LD     34                     // float2 row stride of cpT (pad 33->34)

#define K4 ((float)(1.0 / 7.0))
#define K5 ((float)(2.0 / 7.0))
#define K6 ((float)(3.0 / 7.0))
#define K7 ((float)(4.0 / 7.0))
#define K8 ((float)(5.0 / 7.0))
#define K9 ((float)(6.0 / 7.0))

__device__ __forceinline__ void knots(float* kf) {
    kf[0] = 0.f; kf[1] = 0.f; kf[2] = 0.f; kf[3] = 0.f;
    kf[4] = K4; kf[5] = K5; kf[6] = K6; kf[7] = K7; kf[8] = K8; kf[9] = K9;
    kf[10] = 1.f; kf[11] = 1.f; kf[12] = 1.f; kf[13] = 1.f;
}

// Faithful f32 mirror of the reference truncated Cox-de Boor.
__device__ __forceinline__ void basis_f32(float t, float* __restrict__ N) {
    float kf[14]; knots(kf);
#pragma unroll
    for (int i = 0; i < 10; ++i) N[i] = (t >= kf[i] && t < kf[i + 1]) ? 1.0f : 0.0f;
#pragma unroll
    for (int r = 1; r <= 3; ++r) {
#pragma unroll
        for (int i = 0; i < 9; ++i) {
            if (i < 10 - r) {
                const float dl = kf[i + r] - kf[i];
                const float dr = kf[i + r + 1] - kf[i + 1];
                const float il = (dl != 0.0f) ? 1.0f / dl : 0.0f;
                const float ir = (dr != 0.0f) ? 1.0f / dr : 0.0f;
                N[i] = ((t - kf[i]) * il) * N[i] + ((kf[i + r + 1] - t) * ir) * N[i + 1];
            }
        }
        N[10 - r] = 0.0f;
    }
}

// Degree-3 basis + analytic first derivative (matches FD to ~1e-4; threshold 0.26).
__device__ __forceinline__ void basis_and_deriv(float t, float* __restrict__ b0,
                                                float* __restrict__ d1) {
    float kf[14]; knots(kf);
    float N[10];
#pragma unroll
    for (int i = 0; i < 10; ++i) N[i] = (t >= kf[i] && t < kf[i + 1]) ? 1.0f : 0.0f;
#pragma unroll
    for (int r = 1; r <= 2; ++r) {
#pragma unroll
        for (int i = 0; i < 9; ++i) {
            if (i < 10 - r) {
                const float dl = kf[i + r] - kf[i];
                const float dr = kf[i + r + 1] - kf[i + 1];
                const float il = (dl != 0.0f) ? 1.0f / dl : 0.0f;
                const float ir = (dr != 0.0f) ? 1.0f / dr : 0.0f;
                N[i] = ((t - kf[i]) * il) * N[i] + ((kf[i + r + 1] - t) * ir) * N[i + 1];
            }
        }
        N[10 - r] = 0.0f;
    }
#pragma unroll
    for (int i = 0; i < 7; ++i) {
        const float dl = kf[i + 3] - kf[i];
        const float dr = kf[i + 4] - kf[i + 1];
        const float il = (dl != 0.0f) ? 3.0f / dl : 0.0f;
        const float ir = (dr != 0.0f) ? 3.0f / dr : 0.0f;
        d1[i] = il * N[i] - ir * N[i + 1];
    }
    d1[7] = 0.f; d1[8] = 0.f; d1[9] = 0.f;
#pragma unroll
    for (int i = 0; i < 7; ++i) {
        const float dl = kf[i + 3] - kf[i];
        const float dr = kf[i + 4] - kf[i + 1];
        const float il = (dl != 0.0f) ? 1.0f / dl : 0.0f;
        const float ir = (dr != 0.0f) ? 1.0f / dr : 0.0f;
        b0[i] = ((t - kf[i]) * il) * N[i] + ((kf[i + 4] - t) * ir) * N[i + 1];
    }
    b0[7] = 0.f; b0[8] = 0.f; b0[9] = 0.f;
}

__global__ __launch_bounds__(THREADS)
void spline_kernel(const float* __restrict__ t_in,
                   const float* __restrict__ cp_in,
                   float* __restrict__ out) {
    __shared__ __align__(16) float  s_basis[PTS_PER_BLOCK * BSTRIDE]; // 24.6 KB
    __shared__ __align__(16) float2 s_cpT[10 * CPT_LD];               // 2.7 KB

    const int tid = threadIdx.x;
    const int blk = blockIdx.x;

    // cpT[i][c] = (cp[2c][i], cp[2c+1][i]); pad column 33 with zeros.
    for (int idx = tid; idx < 10 * CPT_LD; idx += THREADS) {
        const int i = idx / CPT_LD, c = idx - i * CPT_LD;
        s_cpT[idx] = (c < 33)
            ? make_float2(cp_in[(2 * c) * 10 + i], cp_in[(2 * c + 1) * 10 + i])
            : make_float2(0.f, 0.f);
    }

    // ---- Phase 1: per-thread f32 basis + analytic derivative ----
    {
        const int pt = blk * PTS_PER_BLOCK + tid;
        const float t = t_in[pt];
        float b0[10], d1[10];
        basis_and_deriv(t, b0, d1);

        const double td = (double)t;   // rare boundary lanes: faithful one-sided FD
        if (td < 1e-6) {
            float Np[10];
            basis_f32((float)(td + 1e-6), Np);
#pragma unroll
            for (int i = 0; i < 10; ++i) d1[i] = Np[i] * 5.0e5f;
        } else if (td + 1e-6 >= 1.0) {
            float Nm[10];
            basis_f32((float)(td - 1e-6), Nm);
#pragma unroll
            for (int i = 0; i < 10; ++i) d1[i] = -Nm[i] * 5.0e5f;
        }

        float* row = s_basis + tid * BSTRIDE;
#pragma unroll
        for (int i = 0; i < 10; ++i) { row[i] = b0[i]; row[12 + i] = d1[i]; }
    }
    __syncthreads();

    // ---- Phase 2: output-element-centric; every store is a dense 512B wave-store ----
    // Block's pos region = 8448 float2; e2 = m*256+tid; p = e2/33, jk0 = (e2%33)*2.
    float2* __restrict__ op = (float2*)(out + (size_t)blk * (PTS_PER_BLOCK * OUT_PER_PT));
    float2* __restrict__ ov = (float2*)(out + (size_t)TOTF + (size_t)blk * (PTS_PER_BLOCK * OUT_PER_PT));
    float2* __restrict__ oa = (float2*)(out + (size_t)2 * TOTF + (size_t)blk * (PTS_PER_BLOCK * OUT_PER_PT));

#pragma unroll 1
    for (int m = 0; m < 33; ++m) {
        const unsigned e2 = (unsigned)(m * THREADS + tid);   // 0..8447
        const unsigned p  = e2 / 33u;                        // magic-mul
        const unsigned c  = e2 - p * 33u;                    // float2 column 0..32

        const float* __restrict__ brow = s_basis + p * BSTRIDE; // broadcast reads
        float pf_x = 0.f, pf_y = 0.f, vf_x = 0.f, vf_y = 0.f;
#pragma unroll
        for (int i = 0; i < 10; ++i) {
            const float2 cv = s_cpT[i * CPT_LD + c];
            const float b = brow[i];
            const float d = brow[12 + i];
            pf_x += b * cv.x;  pf_y += b * cv.y;
            vf_x += d * cv.x;  vf_y += d * cv.y;
        }
        op[e2] = make_float2(pf_x, pf_y);
        const float2 v = make_float2(vf_x, vf_y);
        ov[e2] = v;
        oa[e2] = v;
    }
}

extern "C" void kernel_launch(void* const* d_in, const int* in_sizes, int n_in,
                              void* d_out, int out_size, void* d_ws, size_t ws_size,
                              hipStream_t stream) {
    const float* t_in  = (const float*)d_in[0];   // [32, 8192] f32
    const float* cp_in = (const float*)d_in[1];   // [22, 3, 10] f32
    float* out = (float*)d_out;

    const int blocks = NPTS / PTS_PER_BLOCK;      // 1024
    spline_kernel<<<blocks, THREADS, 0, stream>>>(t_in, cp_in, out);
}